// Round 1
// baseline (115.308 us; speedup 1.0000x reference)
//
#include <hip/hip_runtime.h>
#include <math.h>

#define EPSV 1e-6f

// One block per (b,f) row. 256 threads x 16 contiguous time steps = T=4096.
// EMA recurrence parallelized as an affine-transform scan:
//   element t>=1: m -> a*m + s*x[t]   (a = 1-s)
//   element t==0: m -> x[0]           (A=0, b=x[0])
__global__ __launch_bounds__(256) void pcen_kernel(
    const float* __restrict__ x,
    const float* __restrict__ s_log,
    const float* __restrict__ alpha_log,
    const float* __restrict__ delta_log,
    const float* __restrict__ r_log,
    float* __restrict__ out,
    int F, int T)
{
    const int row  = blockIdx.x;         // b*F + f
    const int f    = row & (F - 1);      // F is a power of two (128)
    const int tid  = threadIdx.x;        // 0..255
    const int lane = tid & 63;
    const int wid  = tid >> 6;

    const float s     = __expf(s_log[f]);
    const float alpha = __expf(alpha_log[f]);
    const float delta = __expf(delta_log[f]);
    const float r     = __expf(r_log[f]);
    const float a     = 1.0f - s;
    const bool  alpha1 = (alpha == 1.0f);   // block-uniform fast paths
    const bool  r1     = (r == 1.0f);
    const float deltar = r1 ? delta : __powf(delta, r);

    const long long base = (long long)row * (long long)T;
    const float* __restrict__ xrow = x + base;
    float*       __restrict__ orow = out + base;

    const int seg = tid << 4;            // 16 elems / thread, 64B-aligned
    float xv[16];
    {
        const float4* p = (const float4*)(xrow + seg);
        float4 v0 = p[0], v1 = p[1], v2 = p[2], v3 = p[3];
        xv[0]=v0.x;  xv[1]=v0.y;  xv[2]=v0.z;  xv[3]=v0.w;
        xv[4]=v1.x;  xv[5]=v1.y;  xv[6]=v1.z;  xv[7]=v1.w;
        xv[8]=v2.x;  xv[9]=v2.y;  xv[10]=v2.z; xv[11]=v2.w;
        xv[12]=v3.x; xv[13]=v3.y; xv[14]=v3.z; xv[15]=v3.w;
    }

    // ---- local segment affine (A, b): m_out = A*m_in + b over 16 elements
    float A, b;
    if (tid == 0) { A = 0.0f; b = xv[0]; }        // t=0: m = x[0]
    else          { A = a;    b = s * xv[0]; }
#pragma unroll
    for (int i = 1; i < 16; ++i) {
        A = a * A;
        b = a * b + s * xv[i];
    }

    // ---- wave-level inclusive scan of affine composition (Hillis-Steele)
    // compose cur AFTER prefix: A = A_cur*A_pre; b = A_cur*b_pre + b_cur
    float Ai = A, bi = b;
#pragma unroll
    for (int off = 1; off < 64; off <<= 1) {
        float Ap = __shfl_up(Ai, off);
        float bp = __shfl_up(bi, off);
        if (lane >= off) {
            bi = Ai * bp + bi;   // uses old Ai
            Ai = Ai * Ap;
        }
    }

    // ---- cross-wave combine via tiny LDS (4 wave totals)
    __shared__ float wA[4], wB[4];
    if (lane == 63) { wA[wid] = Ai; wB[wid] = bi; }
    __syncthreads();

    // within-wave exclusive prefix
    float Ae = __shfl_up(Ai, 1);
    float be = __shfl_up(bi, 1);
    if (lane == 0) { Ae = 1.0f; be = 0.0f; }

    // accumulate totals of waves 0..wid-1 (in time order), then my wave's
    // exclusive prefix on top: P = Excl ∘ T_{wid-1} ∘ ... ∘ T_0
    float Aacc = 1.0f, bacc = 0.0f;
#pragma unroll
    for (int w = 0; w < 3; ++w) {
        if (w < wid) {
            bacc = wA[w] * bacc + wB[w];
            Aacc = wA[w] * Aacc;
        }
    }
    // apply within-wave exclusive after the wave prefix
    float m = Ae * bacc + be;     // m_before = P(0); A-part irrelevant (thread0 has A=0)

    // ---- recompute m sequentially from the carry, apply PCEN pointwise
#pragma unroll
    for (int i = 0; i < 16; ++i) {
        if (i == 0 && tid == 0) m = xv[0];
        else                    m = a * m + s * xv[i];
        float em = EPSV + m;
        float sm = alpha1 ? __builtin_amdgcn_rcpf(em)
                          : __expf(-alpha * __logf(em));
        float o;
        if (r1) o = xv[i] * sm;                                  // (v+d)^1 - d^1
        else    o = __powf(xv[i] * sm + delta, r) - deltar;
        xv[i] = o;
    }

    {
        float4* q = (float4*)(orow + seg);
        q[0] = make_float4(xv[0],  xv[1],  xv[2],  xv[3]);
        q[1] = make_float4(xv[4],  xv[5],  xv[6],  xv[7]);
        q[2] = make_float4(xv[8],  xv[9],  xv[10], xv[11]);
        q[3] = make_float4(xv[12], xv[13], xv[14], xv[15]);
    }
}

extern "C" void kernel_launch(void* const* d_in, const int* in_sizes, int n_in,
                              void* d_out, int out_size, void* d_ws, size_t ws_size,
                              hipStream_t stream) {
    const float* x         = (const float*)d_in[0];
    const float* s_log     = (const float*)d_in[1];
    const float* alpha_log = (const float*)d_in[2];
    const float* delta_log = (const float*)d_in[3];
    const float* r_log     = (const float*)d_in[4];
    float* out = (float*)d_out;

    const int F = in_sizes[1];           // 128
    const int T = 4096;                  // 256 threads * 16 elems
    const int rows = in_sizes[0] / T;    // B*F = 16384

    pcen_kernel<<<rows, 256, 0, stream>>>(x, s_log, alpha_log, delta_log, r_log,
                                          out, F, T);
}

// Round 2
// 98.011 us; speedup vs baseline: 1.1765x; 1.1765x over previous
//
#include <hip/hip_runtime.h>
#include <math.h>

#define EPSV 1e-6f

// One block per (b,f) row. 1024 threads x 4 contiguous time steps = T=4096.
// Per-thread segment = exactly one float4 (16B) -> lane stride 16B on both
// load and store: perfectly coalesced, no cache-line touch amplification.
//
// EMA recurrence parallelized as an affine-transform scan:
//   element t>=1: m -> a*m + s*x[t]   (a = 1-s)
//   element t==0: m -> x[0]           (A=0, b=x[0])  -> initial value irrelevant
__global__ __launch_bounds__(1024) void pcen_kernel(
    const float* __restrict__ x,
    const float* __restrict__ s_log,
    const float* __restrict__ alpha_log,
    const float* __restrict__ delta_log,
    const float* __restrict__ r_log,
    float* __restrict__ out,
    int F, int T)
{
    const int row  = blockIdx.x;         // b*F + f
    const int f    = row & (F - 1);      // F is a power of two (128)
    const int tid  = threadIdx.x;        // 0..1023
    const int lane = tid & 63;
    const int wid  = tid >> 6;           // 0..15

    const float s     = __expf(s_log[f]);
    const float alpha = __expf(alpha_log[f]);
    const float delta = __expf(delta_log[f]);
    const float r     = __expf(r_log[f]);
    const float a     = 1.0f - s;
    const bool  alpha1 = (alpha == 1.0f);   // block-uniform fast paths
    const bool  r1     = (r == 1.0f);
    const float deltar = r1 ? delta : __powf(delta, r);

    const long long base = (long long)row * (long long)T;
    const float* __restrict__ xrow = x + base;
    float*       __restrict__ orow = out + base;

    const int seg = tid << 2;            // 4 elems / thread, 16B-aligned
    float xv[4];
    {
        float4 v = *(const float4*)(xrow + seg);
        xv[0] = v.x; xv[1] = v.y; xv[2] = v.z; xv[3] = v.w;
    }

    // ---- local segment affine (A, b): m_out = A*m_in + b over 4 elements
    float A, b;
    if (tid == 0) { A = 0.0f; b = xv[0]; }        // t=0: m = x[0]
    else          { A = a;    b = s * xv[0]; }
#pragma unroll
    for (int i = 1; i < 4; ++i) {
        A = a * A;
        b = a * b + s * xv[i];
    }

    // ---- wave-level inclusive scan of affine composition (Hillis-Steele)
    // compose cur AFTER prefix: A = A_cur*A_pre; b = A_cur*b_pre + b_cur
    float Ai = A, bi = b;
#pragma unroll
    for (int off = 1; off < 64; off <<= 1) {
        float Ap = __shfl_up(Ai, off);
        float bp = __shfl_up(bi, off);
        if (lane >= off) {
            bi = Ai * bp + bi;   // uses pre-update Ai
            Ai = Ai * Ap;
        }
    }

    // ---- cross-wave combine: wave totals -> LDS, wave 0 scans 16 entries
    __shared__ float wA[16], wB[16];     // inclusive totals per wave
    __shared__ float wAe[16], wBe[16];   // exclusive prefixes per wave
    if (lane == 63) { wA[wid] = Ai; wB[wid] = bi; }
    __syncthreads();

    if (wid == 0) {
        float Aw = (lane < 16) ? wA[lane] : 1.0f;
        float bw = (lane < 16) ? wB[lane] : 0.0f;
#pragma unroll
        for (int off = 1; off < 16; off <<= 1) {
            float Ap = __shfl_up(Aw, off);
            float bp = __shfl_up(bw, off);
            if (lane >= off) {
                bw = Aw * bp + bw;
                Aw = Aw * Ap;
            }
        }
        if (lane < 16) {
            // exclusive = inclusive of lane-1; lane 0 = identity
            float AeW = __shfl_up(Aw, 1);
            float beW = __shfl_up(bw, 1);
            if (lane == 0) { AeW = 1.0f; beW = 0.0f; }
            wAe[lane] = AeW; wBe[lane] = beW;
        }
    }
    __syncthreads();

    // within-wave exclusive prefix (from inclusive scan values)
    float Ae = __shfl_up(Ai, 1);
    float be = __shfl_up(bi, 1);
    if (lane == 0) { Ae = 1.0f; be = 0.0f; }

    // carry into this thread: apply wave-prefix (eval at 0 -> bw), then
    // within-wave exclusive. Thread 0's A=0 in the chain makes init irrelevant.
    const float bwp = wBe[wid];          // broadcast read (uniform per wave)
    float m = Ae * bwp + be;

    // ---- recompute m sequentially from the carry, apply PCEN pointwise
#pragma unroll
    for (int i = 0; i < 4; ++i) {
        if (i == 0 && tid == 0) m = xv[0];
        else                    m = a * m + s * xv[i];
        float em = EPSV + m;
        float sm = alpha1 ? __builtin_amdgcn_rcpf(em)
                          : __expf(-alpha * __logf(em));
        float o;
        if (r1) o = xv[i] * sm;                                  // (v+d)^1 - d^1
        else    o = __powf(xv[i] * sm + delta, r) - deltar;
        xv[i] = o;
    }

    {
        *(float4*)(orow + seg) = make_float4(xv[0], xv[1], xv[2], xv[3]);
    }
}

extern "C" void kernel_launch(void* const* d_in, const int* in_sizes, int n_in,
                              void* d_out, int out_size, void* d_ws, size_t ws_size,
                              hipStream_t stream) {
    const float* x         = (const float*)d_in[0];
    const float* s_log     = (const float*)d_in[1];
    const float* alpha_log = (const float*)d_in[2];
    const float* delta_log = (const float*)d_in[3];
    const float* r_log     = (const float*)d_in[4];
    float* out = (float*)d_out;

    const int F = in_sizes[1];           // 128
    const int T = 4096;                  // 1024 threads * 4 elems
    const int rows = in_sizes[0] / T;    // B*F = 16384

    pcen_kernel<<<rows, 1024, 0, stream>>>(x, s_log, alpha_log, delta_log, r_log,
                                           out, F, T);
}